// Round 4
// baseline (148.740 us; speedup 1.0000x reference)
//
#include <hip/hip_runtime.h>
#include <math.h>

#define NB 8
#define CH 16
#define LL 1024
#define DD 7
#define HH 16

typedef float  v2f  __attribute__((ext_vector_type(2)));
typedef float  v4f  __attribute__((ext_vector_type(4)));
typedef float  v16f __attribute__((ext_vector_type(16)));
typedef short  v8s  __attribute__((ext_vector_type(8)));

#if __has_builtin(__builtin_amdgcn_exp2f)
#define EXP2F(x) __builtin_amdgcn_exp2f(x)
#else
#define EXP2F(x) exp2f(x)
#endif

__device__ inline unsigned bf16_rne(float f) {
    unsigned u = __builtin_bit_cast(unsigned, f);
    return (u + 0x7fffu + ((u >> 16) & 1u)) >> 16;
}
__device__ inline unsigned pack_trunc(float a, float b) {
    unsigned ua = __builtin_bit_cast(unsigned, a);
    unsigned ub = __builtin_bit_cast(unsigned, b);
    return (ua >> 16) | (ub & 0xffff0000u);
}

// ---------------------------------------------------------------------------
// Kernel 1: QKV projection (fp32 math via v_pk_fma_f32 pairs, bf16 output
// padded [mat][n][h][1024][8]). Q pre-scaled by log2(e)/32.
// grid = 3*NB*16 = 384 blocks, 256 threads.
// ---------------------------------------------------------------------------
__global__ __launch_bounds__(256, 2) void qkv_proj(
    const float* __restrict__ x,
    const float* __restrict__ Wq, const float* __restrict__ bq,
    const float* __restrict__ Wk, const float* __restrict__ bk,
    const float* __restrict__ Wv, const float* __restrict__ bv,
    unsigned short* __restrict__ qkvb)
{
    __shared__ __align__(16) float Ws[112 * 112];   // W[j][i], i contiguous
    __shared__ __align__(16) float xt[64 * 116];    // xf rows, stride 116

    int bx  = blockIdx.x;
    int mat = bx / (NB * 16);
    int rem = bx % (NB * 16);
    int n   = rem / 16;
    int l0  = (rem % 16) * 64;

    const float* W = (mat == 0) ? Wq : (mat == 1) ? Wk : Wv;
    const float* b = (mat == 0) ? bq : (mat == 1) ? bk : bv;

    int tid = threadIdx.x;

    {   // W staging: 3136 uint4, coalesced
        const uint4* src = (const uint4*)W;
        uint4* dst = (uint4*)Ws;
        for (int i = tid; i < 3136; i += 256) dst[i] = src[i];
    }
    for (int idx = tid; idx < 64 * 112; idx += 256) {
        int c  = idx / 448;
        int r  = idx - c * 448;
        int l  = r / 7;
        int dd = r - l * 7;
        xt[l * 116 + c * 7 + dd] = x[((n * CH + c) * LL + l0 + l) * DD + dd];
    }
    __syncthreads();

    int jh = tid >> 4;   // head (wave-slow -> W reads broadcast)
    int lg = tid & 15;   // row group (wave-fast -> coalesced stores)

    v2f acc2[2][7];
    #pragma unroll
    for (int j = 0; j < 7; ++j) {
        float bj = b[jh * 7 + j];
        acc2[0][j] = (v2f){bj, bj};
        acc2[1][j] = (v2f){bj, bj};
    }

    const v4f* Wv4 = (const v4f*)Ws;
    const v4f* Xv4 = (const v4f*)xt;

    for (int i4 = 0; i4 < 28; ++i4) {
        v4f wv[7];
        #pragma unroll
        for (int j = 0; j < 7; ++j) wv[j] = Wv4[(jh * 7 + j) * 28 + i4];
        v4f x0 = Xv4[(0  + lg) * 29 + i4];
        v4f x1 = Xv4[(16 + lg) * 29 + i4];
        v4f x2 = Xv4[(32 + lg) * 29 + i4];
        v4f x3 = Xv4[(48 + lg) * 29 + i4];
        #pragma unroll
        for (int f = 0; f < 4; ++f) {
            v2f xa = (v2f){x0[f], x1[f]};
            v2f xb = (v2f){x2[f], x3[f]};
            #pragma unroll
            for (int j = 0; j < 7; ++j) {
                v2f wj = (v2f){wv[j][f], wv[j][f]};
                acc2[0][j] += xa * wj;      // v_pk_fma_f32
                acc2[1][j] += xb * wj;
            }
        }
    }

    const float scale = (mat == 0) ? 0.0450842200277801f /* log2(e)/32 */ : 1.0f;
    #pragma unroll
    for (int rp = 0; rp < 2; ++rp) {
        #pragma unroll
        for (int e = 0; e < 2; ++e) {
            int r = rp * 2 + e;
            float a0 = acc2[rp][0][e] * scale, a1 = acc2[rp][1][e] * scale;
            float a2 = acc2[rp][2][e] * scale, a3 = acc2[rp][3][e] * scale;
            float a4 = acc2[rp][4][e] * scale, a5 = acc2[rp][5][e] * scale;
            float a6 = acc2[rp][6][e] * scale;
            unsigned d0 = bf16_rne(a0) | (bf16_rne(a1) << 16);
            unsigned d1 = bf16_rne(a2) | (bf16_rne(a3) << 16);
            unsigned d2 = bf16_rne(a4) | (bf16_rne(a5) << 16);
            unsigned d3 = bf16_rne(a6);                     // pad col 7 = 0
            int row = l0 + r * 16 + lg;
            uint4* dst = (uint4*)qkvb + ((size_t)(mat * NB + n) * HH + jh) * LL + row;
            *dst = make_uint4(d0, d1, d2, d3);
        }
    }
}

// ---------------------------------------------------------------------------
// Kernel 2: MFMA flash attention, software-pipelined.
//  S^T = mfma_32x32x16(A=K, B=Q); key->slot perm makes lane's 16 exp'd values
//  contiguous (2x ds_write_b128). P is DOUBLE-BUFFERED in LDS: PV(c-1) reads
//  the other buffer while S/exp/pack/write of chunk c proceeds. kf/vf are
//  register-prefetched one chunk ahead. V transposed global->reg->LDS (no
//  LDS temp). V col 7 == 1.0 => softmax denominator free in output col 7.
// grid = 512 blocks = exactly 2/CU, 256 thr; wave owns 64 q rows.
// ---------------------------------------------------------------------------
__global__ __launch_bounds__(256, 2) void attn(
    const unsigned short* __restrict__ qkvb, float* __restrict__ out)
{
    __shared__ __align__(16) unsigned short Kl[LL * 8];            // 16 KB
    __shared__ __align__(16) unsigned short Vt[8 * 1040];          // 16.25 KB
    __shared__ __align__(16) unsigned short Pb[2 * 4 * 64 * 36];   // 36 KB

    int bx = blockIdx.x;
    int qt = bx & 3, h = (bx >> 2) & 15, n = bx >> 6;
    int tid  = threadIdx.x;
    int wave = tid >> 6, lane = tid & 63;
    int l31 = lane & 31, g5 = lane >> 5, l15 = lane & 15, l4 = lane >> 4;

    const unsigned short* Qg = qkvb + (size_t)((0 * NB + n) * HH + h) * (LL * 8);
    const unsigned short* Kg = qkvb + (size_t)((1 * NB + n) * HH + h) * (LL * 8);
    const unsigned short* Vg = qkvb + (size_t)((2 * NB + n) * HH + h) * (LL * 8);

    {   // stage K -> Kl (coalesced 16B)
        const uint4* Ks = (const uint4*)Kg;
        uint4* Kd = (uint4*)Kl;
        #pragma unroll
        for (int it = 0; it < 4; ++it) Kd[tid + it * 256] = Ks[tid + it * 256];
    }
    {   // transpose + slot-permute V: global -> regs -> Vt[8][1040]
        const uint4* Vs = (const uint4*)Vg;
        uint4 r0 = Vs[4 * tid], r1 = Vs[4 * tid + 1];
        uint4 r2 = Vs[4 * tid + 2], r3 = Vs[4 * tid + 3];
        const unsigned* p0 = (const unsigned*)&r0;
        const unsigned* p1 = (const unsigned*)&r1;
        const unsigned* p2 = (const unsigned*)&r2;
        const unsigned* p3 = (const unsigned*)&r3;
        int col = ((tid >> 3) << 5) + ((tid & 1) << 4) + (((tid >> 1) & 3) << 2);
        #pragma unroll
        for (int d = 0; d < 7; ++d) {
            unsigned a0 = p0[d >> 1], a1 = p1[d >> 1], a2 = p2[d >> 1], a3 = p3[d >> 1];
            unsigned w0, w1;
            if (d & 1) { w0 = (a0 >> 16) | (a1 & 0xffff0000u); w1 = (a2 >> 16) | (a3 & 0xffff0000u); }
            else       { w0 = (a0 & 0xffffu) | (a1 << 16);     w1 = (a2 & 0xffffu) | (a3 << 16); }
            *(uint2*)&Vt[d * 1040 + col] = make_uint2(w0, w1);
        }
        *(uint2*)&Vt[7 * 1040 + col] = make_uint2(0x3f803f80u, 0x3f803f80u);
    }
    __syncthreads();

    int qbase = qt * 256 + wave * 64;
    v8s zero8 = {0, 0, 0, 0, 0, 0, 0, 0};
    v8s qf0 = (lane < 32) ? *(const v8s*)(Qg + (size_t)(qbase + l31) * 8)      : zero8;
    v8s qf1 = (lane < 32) ? *(const v8s*)(Qg + (size_t)(qbase + 32 + l31) * 8) : zero8;

    v4f acc[4];
    #pragma unroll
    for (int st = 0; st < 4; ++st) acc[st] = (v4f){0.f, 0.f, 0.f, 0.f};

    v8s kf  = (lane < 32) ? *(const v8s*)(Kl + l31 * 8) : zero8;   // chunk 0
    v8s vfp = zero8;   // V of chunk c-1 (set at end of each iter)

    #pragma unroll 2
    for (int c = 0; c < 32; ++c) {
        v16f s0 = __builtin_amdgcn_mfma_f32_32x32x16_bf16(kf, qf0, (v16f){}, 0, 0, 0);
        v16f s1 = __builtin_amdgcn_mfma_f32_32x32x16_bf16(kf, qf1, (v16f){}, 0, 0, 0);

        // prefetch next K chunk + this chunk's V (used next iteration)
        v8s kfn = (c < 31 && lane < 32) ? *(const v8s*)(Kl + ((c + 1) * 32 + l31) * 8) : zero8;
        v8s vfc = (l15 < 8) ? *(const v8s*)(Vt + l15 * 1040 + c * 32 + l4 * 8) : zero8;

        unsigned short* Pw = Pb + ((c & 1) * 4 + wave) * (64 * 36);
        {
            unsigned short* dst = Pw + l31 * 36 + (g5 << 4);
            uint4 wa, wb;
            wa.x = pack_trunc(EXP2F(s0[0]),  EXP2F(s0[1]));
            wa.y = pack_trunc(EXP2F(s0[2]),  EXP2F(s0[3]));
            wa.z = pack_trunc(EXP2F(s0[4]),  EXP2F(s0[5]));
            wa.w = pack_trunc(EXP2F(s0[6]),  EXP2F(s0[7]));
            wb.x = pack_trunc(EXP2F(s0[8]),  EXP2F(s0[9]));
            wb.y = pack_trunc(EXP2F(s0[10]), EXP2F(s0[11]));
            wb.z = pack_trunc(EXP2F(s0[12]), EXP2F(s0[13]));
            wb.w = pack_trunc(EXP2F(s0[14]), EXP2F(s0[15]));
            *(uint4*)dst       = wa;
            *(uint4*)(dst + 8) = wb;
        }
        {
            unsigned short* dst = Pw + (32 + l31) * 36 + (g5 << 4);
            uint4 wa, wb;
            wa.x = pack_trunc(EXP2F(s1[0]),  EXP2F(s1[1]));
            wa.y = pack_trunc(EXP2F(s1[2]),  EXP2F(s1[3]));
            wa.z = pack_trunc(EXP2F(s1[4]),  EXP2F(s1[5]));
            wa.w = pack_trunc(EXP2F(s1[6]),  EXP2F(s1[7]));
            wb.x = pack_trunc(EXP2F(s1[8]),  EXP2F(s1[9]));
            wb.y = pack_trunc(EXP2F(s1[10]), EXP2F(s1[11]));
            wb.z = pack_trunc(EXP2F(s1[12]), EXP2F(s1[13]));
            wb.w = pack_trunc(EXP2F(s1[14]), EXP2F(s1[15]));
            *(uint4*)dst       = wa;
            *(uint4*)(dst + 8) = wb;
        }

        if (c > 0) {   // PV for chunk c-1 from the OTHER buffer
            const unsigned short* Pr = Pb + (((c - 1) & 1) * 4 + wave) * (64 * 36);
            #pragma unroll
            for (int st = 0; st < 4; ++st) {
                v8s pf = *(const v8s*)(Pr + (st * 16 + l15) * 36 + l4 * 8);
                acc[st] = __builtin_amdgcn_mfma_f32_16x16x32_bf16(pf, vfp, acc[st], 0, 0, 0);
            }
        }
        kf  = kfn;
        vfp = vfc;
    }
    {   // drain: PV for chunk 31
        const unsigned short* Pr = Pb + ((31 & 1) * 4 + wave) * (64 * 36);
        #pragma unroll
        for (int st = 0; st < 4; ++st) {
            v8s pf = *(const v8s*)(Pr + (st * 16 + l15) * 36 + l4 * 8);
            acc[st] = __builtin_amdgcn_mfma_f32_16x16x32_bf16(pf, vfp, acc[st], 0, 0, 0);
        }
    }

    // epilogue: col 7 of acc = rowsum; divide and store dims 0..6
    size_t obase = (size_t)(n * HH + h) * LL * 7;
    #pragma unroll
    for (int st = 0; st < 4; ++st) {
        #pragma unroll
        for (int r = 0; r < 4; ++r) {
            float val = acc[st][r];
            float rs  = __shfl(val, 7, 16);   // broadcast col-7 within 16-lane seg
            if (l15 < 7)
                out[obase + (size_t)(qbase + st * 16 + l4 * 4 + r) * 7 + l15] = val / rs;
        }
    }
}

extern "C" void kernel_launch(void* const* d_in, const int* in_sizes, int n_in,
                              void* d_out, int out_size, void* d_ws, size_t ws_size,
                              hipStream_t stream) {
    const float* x  = (const float*)d_in[0];
    const float* Wq = (const float*)d_in[1];
    const float* bq = (const float*)d_in[2];
    const float* Wk = (const float*)d_in[3];
    const float* bk = (const float*)d_in[4];
    const float* Wv = (const float*)d_in[5];
    const float* bv = (const float*)d_in[6];
    unsigned short* qkvb = (unsigned short*)d_ws;  // [3][8][16][1024][8] bf16 = 6 MB
    float* o = (float*)d_out;

    qkv_proj<<<dim3(3 * NB * 16), dim3(256), 0, stream>>>(x, Wq, bq, Wk, bk, Wv, bv, qkvb);
    attn<<<dim3(NB * HH * 4), dim3(256), 0, stream>>>(qkvb, o);
}

// Round 5
// 106.647 us; speedup vs baseline: 1.3947x; 1.3947x over previous
//
#include <hip/hip_runtime.h>
#include <math.h>

#define NB 8
#define CH 16
#define LL 1024
#define DD 7
#define HH 16

typedef float    v2f  __attribute__((ext_vector_type(2)));
typedef float    v4f  __attribute__((ext_vector_type(4)));
typedef float    v16f __attribute__((ext_vector_type(16)));
typedef short    v8s  __attribute__((ext_vector_type(8)));
typedef unsigned v4u  __attribute__((ext_vector_type(4)));

#if __has_builtin(__builtin_amdgcn_exp2f)
#define EXP2F(x) __builtin_amdgcn_exp2f(x)
#else
#define EXP2F(x) exp2f(x)
#endif

__device__ inline unsigned bf16_rne(float f) {
    unsigned u = __builtin_bit_cast(unsigned, f);
    return (u + 0x7fffu + ((u >> 16) & 1u)) >> 16;
}
__device__ inline unsigned pack_trunc(float a, float b) {
    unsigned ua = __builtin_bit_cast(unsigned, a);
    unsigned ub = __builtin_bit_cast(unsigned, b);
    return (ua >> 16) | (ub & 0xffff0000u);
}

// ---------------------------------------------------------------------------
// Kernel 1: QKV projection (fp32 math via v_pk_fma_f32 pairs, bf16 output
// padded [mat][n][h][1024][8]). Q pre-scaled by log2(e)/32.
// grid = 3*NB*16 = 384 blocks, 256 threads.
// ---------------------------------------------------------------------------
__global__ __launch_bounds__(256, 2) void qkv_proj(
    const float* __restrict__ x,
    const float* __restrict__ Wq, const float* __restrict__ bq,
    const float* __restrict__ Wk, const float* __restrict__ bk,
    const float* __restrict__ Wv, const float* __restrict__ bv,
    unsigned short* __restrict__ qkvb)
{
    __shared__ __align__(16) float Ws[112 * 112];   // W[j][i], i contiguous
    __shared__ __align__(16) float xt[64 * 116];    // xf rows, stride 116

    int bx  = blockIdx.x;
    int mat = bx / (NB * 16);
    int rem = bx % (NB * 16);
    int n   = rem / 16;
    int l0  = (rem % 16) * 64;

    const float* W = (mat == 0) ? Wq : (mat == 1) ? Wk : Wv;
    const float* b = (mat == 0) ? bq : (mat == 1) ? bk : bv;

    int tid = threadIdx.x;

    {   // W staging: 3136 uint4, coalesced
        const uint4* src = (const uint4*)W;
        uint4* dst = (uint4*)Ws;
        for (int i = tid; i < 3136; i += 256) dst[i] = src[i];
    }
    for (int idx = tid; idx < 64 * 112; idx += 256) {
        int c  = idx / 448;
        int r  = idx - c * 448;
        int l  = r / 7;
        int dd = r - l * 7;
        xt[l * 116 + c * 7 + dd] = x[((n * CH + c) * LL + l0 + l) * DD + dd];
    }
    __syncthreads();

    int jh = tid >> 4;   // head (wave-slow -> W reads broadcast)
    int lg = tid & 15;   // row group (wave-fast -> coalesced stores)

    v2f acc2[2][7];
    #pragma unroll
    for (int j = 0; j < 7; ++j) {
        float bj = b[jh * 7 + j];
        acc2[0][j] = (v2f){bj, bj};
        acc2[1][j] = (v2f){bj, bj};
    }

    const v4f* Wv4 = (const v4f*)Ws;
    const v4f* Xv4 = (const v4f*)xt;

    for (int i4 = 0; i4 < 28; ++i4) {
        v4f wv[7];
        #pragma unroll
        for (int j = 0; j < 7; ++j) wv[j] = Wv4[(jh * 7 + j) * 28 + i4];
        v4f x0 = Xv4[(0  + lg) * 29 + i4];
        v4f x1 = Xv4[(16 + lg) * 29 + i4];
        v4f x2 = Xv4[(32 + lg) * 29 + i4];
        v4f x3 = Xv4[(48 + lg) * 29 + i4];
        #pragma unroll
        for (int f = 0; f < 4; ++f) {
            v2f xa = (v2f){x0[f], x1[f]};
            v2f xb = (v2f){x2[f], x3[f]};
            #pragma unroll
            for (int j = 0; j < 7; ++j) {
                v2f wj = (v2f){wv[j][f], wv[j][f]};
                acc2[0][j] += xa * wj;      // v_pk_fma_f32
                acc2[1][j] += xb * wj;
            }
        }
    }

    const float scale = (mat == 0) ? 0.0450842200277801f /* log2(e)/32 */ : 1.0f;
    #pragma unroll
    for (int rp = 0; rp < 2; ++rp) {
        #pragma unroll
        for (int e = 0; e < 2; ++e) {
            int r = rp * 2 + e;
            float a0 = acc2[rp][0][e] * scale, a1 = acc2[rp][1][e] * scale;
            float a2 = acc2[rp][2][e] * scale, a3 = acc2[rp][3][e] * scale;
            float a4 = acc2[rp][4][e] * scale, a5 = acc2[rp][5][e] * scale;
            float a6 = acc2[rp][6][e] * scale;
            unsigned d0 = bf16_rne(a0) | (bf16_rne(a1) << 16);
            unsigned d1 = bf16_rne(a2) | (bf16_rne(a3) << 16);
            unsigned d2 = bf16_rne(a4) | (bf16_rne(a5) << 16);
            unsigned d3 = bf16_rne(a6);                     // pad col 7 = 0
            int row = l0 + r * 16 + lg;
            uint4* dst = (uint4*)qkvb + ((size_t)(mat * NB + n) * HH + jh) * LL + row;
            *dst = make_uint4(d0, d1, d2, d3);
        }
    }
}

// ---------------------------------------------------------------------------
// Kernel 2: MFMA flash attention, FULLY REGISTER-RESIDENT P (no LDS round trip).
//  S^T = mfma_32x32x16(A=K, B=Q): lane(g5,l31) holds S^T[key][q=l31] for 16
//  keys, key = (reg&3)+8*(reg>>2)+4*g5. exp+pack in regs is ALREADY a valid
//  B-operand for the next 32x32x16: B k-index = 8*g5+j covers key set
//  K(k) = (k&3)+8*((k>>2)&1)+4*(k>>3) — that permutation is absorbed into
//  Vt's column order at staging (bits 2<->3 of the chunk-local key index).
//  PV: O^T = mfma(A=V^T rows 0..7 (+ones row 7), B=P^T). acc rows 0-3 (g5=0)
//  = dims 0-3, rows 4-7 (g5=1) = dims 4-6 + denominator (dim7 = ones).
// grid = NB*HH*8 = 1024 blocks (n,h,qtile 128), 256 thr; wave owns 32 q rows.
// LDS = 33 KB -> 4 blocks/CU (16 waves/CU).
// ---------------------------------------------------------------------------
__global__ __launch_bounds__(256, 4) void attn(
    const unsigned short* __restrict__ qkvb, float* __restrict__ out)
{
    __shared__ __align__(16) unsigned short Kl[LL * 8];     // 16 KB
    __shared__ __align__(16) unsigned short Vt[8 * 1048];   // 16.4 KB, slot-permuted

    int bx = blockIdx.x;
    int qt = bx & 7, h = (bx >> 3) & 15, n = bx >> 7;
    int tid  = threadIdx.x;
    int wave = tid >> 6, lane = tid & 63;
    int l31 = lane & 31, g5 = lane >> 5;

    const unsigned short* Qg = qkvb + (size_t)((0 * NB + n) * HH + h) * (LL * 8);
    const unsigned short* Kg = qkvb + (size_t)((1 * NB + n) * HH + h) * (LL * 8);
    const unsigned short* Vg = qkvb + (size_t)((2 * NB + n) * HH + h) * (LL * 8);

    {   // stage K -> Kl (coalesced 16B)
        const uint4* Ks = (const uint4*)Kg;
        uint4* Kd = (uint4*)Kl;
        #pragma unroll
        for (int it = 0; it < 4; ++it) Kd[tid + it * 256] = Ks[tid + it * 256];
    }
    {   // transpose + slot-permute V: global -> regs -> Vt[8][1048]
        // thread t owns keys 4t..4t+3; slot = key with chunk-local bits 2<->3 swapped
        const uint4* Vs = (const uint4*)Vg;
        uint4 r0 = Vs[4 * tid], r1 = Vs[4 * tid + 1];
        uint4 r2 = Vs[4 * tid + 2], r3 = Vs[4 * tid + 3];
        const unsigned* p0 = (const unsigned*)&r0;
        const unsigned* p1 = (const unsigned*)&r1;
        const unsigned* p2 = (const unsigned*)&r2;
        const unsigned* p3 = (const unsigned*)&r3;
        int col = ((tid >> 3) << 5) + ((tid & 1) << 3) + (((tid >> 1) & 1) << 2)
                + (((tid >> 2) & 1) << 4);
        #pragma unroll
        for (int d = 0; d < 7; ++d) {
            unsigned a0 = p0[d >> 1], a1 = p1[d >> 1], a2 = p2[d >> 1], a3 = p3[d >> 1];
            unsigned w0, w1;
            if (d & 1) { w0 = (a0 >> 16) | (a1 & 0xffff0000u); w1 = (a2 >> 16) | (a3 & 0xffff0000u); }
            else       { w0 = (a0 & 0xffffu) | (a1 << 16);     w1 = (a2 & 0xffffu) | (a3 << 16); }
            *(uint2*)&Vt[d * 1048 + col] = make_uint2(w0, w1);
        }
        *(uint2*)&Vt[7 * 1048 + col] = make_uint2(0x3f803f80u, 0x3f803f80u);  // ones row
    }
    __syncthreads();

    int q = qt * 128 + wave * 32 + l31;
    v8s zero8 = {0, 0, 0, 0, 0, 0, 0, 0};
    v8s qf = (lane < 32) ? *(const v8s*)(Qg + (size_t)q * 8) : zero8;

    const unsigned short* Vrow = Vt + (l31 & 7) * 1048 + g5 * 8;  // rows 8+ -> garbage, ignored
    v16f acc = {};

    v8s kf = (lane < 32) ? *(const v8s*)(Kl + l31 * 8) : zero8;   // chunk 0 prefetch

    #pragma unroll 4
    for (int c = 0; c < 32; ++c) {
        v16f s = __builtin_amdgcn_mfma_f32_32x32x16_bf16(kf, qf, (v16f){}, 0, 0, 0);
        if (c < 31)
            kf = (lane < 32) ? *(const v8s*)(Kl + ((c + 1) * 32 + l31) * 8) : zero8;
        v8s va1 = *(const v8s*)(Vrow + c * 32);        // k=0..15 (slots)
        v8s va2 = *(const v8s*)(Vrow + c * 32 + 16);   // k=16..31

        unsigned pk[8];
        #pragma unroll
        for (int p = 0; p < 8; ++p)
            pk[p] = pack_trunc(EXP2F(s[2 * p]), EXP2F(s[2 * p + 1]));
        v8s pA = __builtin_bit_cast(v8s, (v4u){pk[0], pk[1], pk[2], pk[3]});
        v8s pB = __builtin_bit_cast(v8s, (v4u){pk[4], pk[5], pk[6], pk[7]});

        acc = __builtin_amdgcn_mfma_f32_32x32x16_bf16(va1, pA, acc, 0, 0, 0);
        acc = __builtin_amdgcn_mfma_f32_32x32x16_bf16(va2, pB, acc, 0, 0, 0);
    }

    // epilogue: acc reg r = O^T[dim = 4*g5 + r][q] (pre-normalize);
    // denominator = O^T[7][q] = upper-half lanes' reg 3.
    float rs = __shfl(acc[3], 32 + l31, 64);
    float* base = out + (size_t)(n * HH + h) * LL * 7 + (size_t)q * 7;
    #pragma unroll
    for (int r = 0; r < 4; ++r) {
        int dim = 4 * g5 + r;
        if (dim < 7) base[dim] = acc[r] / rs;
    }
}

extern "C" void kernel_launch(void* const* d_in, const int* in_sizes, int n_in,
                              void* d_out, int out_size, void* d_ws, size_t ws_size,
                              hipStream_t stream) {
    const float* x  = (const float*)d_in[0];
    const float* Wq = (const float*)d_in[1];
    const float* bq = (const float*)d_in[2];
    const float* Wk = (const float*)d_in[3];
    const float* bk = (const float*)d_in[4];
    const float* Wv = (const float*)d_in[5];
    const float* bv = (const float*)d_in[6];
    unsigned short* qkvb = (unsigned short*)d_ws;  // [3][8][16][1024][8] bf16 = 6 MB
    float* o = (float*)d_out;

    qkv_proj<<<dim3(3 * NB * 16), dim3(256), 0, stream>>>(x, Wq, bq, Wk, bk, Wv, bv, qkvb);
    attn<<<dim3(NB * HH * 8), dim3(256), 0, stream>>>(qkvb, o);
}

// Round 6
// 101.564 us; speedup vs baseline: 1.4645x; 1.0501x over previous
//
#include <hip/hip_runtime.h>
#include <math.h>

#define NB 8
#define CH 16
#define LL 1024
#define DD 7
#define HH 16

typedef float    v2f  __attribute__((ext_vector_type(2)));
typedef float    v4f  __attribute__((ext_vector_type(4)));
typedef float    v16f __attribute__((ext_vector_type(16)));
typedef short    v8s  __attribute__((ext_vector_type(8)));
typedef unsigned v4u  __attribute__((ext_vector_type(4)));

#if __has_builtin(__builtin_amdgcn_exp2f)
#define EXP2F(x) __builtin_amdgcn_exp2f(x)
#else
#define EXP2F(x) exp2f(x)
#endif

__device__ inline unsigned bf16_rne(float f) {
    unsigned u = __builtin_bit_cast(unsigned, f);
    return (u + 0x7fffu + ((u >> 16) & 1u)) >> 16;
}
__device__ inline unsigned pack_trunc(float a, float b) {
    unsigned ua = __builtin_bit_cast(unsigned, a);
    unsigned ub = __builtin_bit_cast(unsigned, b);
    return (ua >> 16) | (ub & 0xffff0000u);
}

// ---------------------------------------------------------------------------
// Kernel 1: QKV projection via MFMA (bf16 inputs, fp32 accumulate).
//  C[l][j] = sum_i xf[l][i] * W[j][i]; A = x (m=l), B = W (n=j), K padded to
//  128 with zeros. LDS: xb[64][136] bf16, Wb[112][136] bf16 (stride 136 =
//  bank-spread, 16B-aligned frags). Wave owns 16 l-rows: A-frags loaded once
//  (4 ds_read_b128), reused over 7 j-tiles x 4 K-slices = 28 MFMA + 28 B-reads.
//  D layout: col j = lane&15, row l = (lane>>4)*4 + reg.
//  Epilogue: +bias, Q scaled by log2(e)/32, bf16 store; pad slot 7 zeroed.
// grid = 3*NB*16 = 384 blocks, 256 threads.
// ---------------------------------------------------------------------------
__global__ __launch_bounds__(256, 2) void qkv_proj(
    const float* __restrict__ x,
    const float* __restrict__ Wq, const float* __restrict__ bq,
    const float* __restrict__ Wk, const float* __restrict__ bk,
    const float* __restrict__ Wv, const float* __restrict__ bv,
    unsigned short* __restrict__ qkvb)
{
    __shared__ __align__(16) unsigned short Wb[112 * 136];  // 29.8 KB
    __shared__ __align__(16) unsigned short xb[64 * 136];   // 17.0 KB

    int bx  = blockIdx.x;
    int mat = bx / (NB * 16);
    int rem = bx % (NB * 16);
    int n   = rem / 16;
    int l0  = (rem % 16) * 64;

    const float* W = (mat == 0) ? Wq : (mat == 1) ? Wk : Wv;
    const float* b = (mat == 0) ? bq : (mat == 1) ? bk : bv;

    int tid = threadIdx.x;

    // stage W -> bf16 LDS (float4 reads, uint2 writes)
    {
        const float4* Wsrc = (const float4*)W;
        for (int i4 = tid; i4 < 3136; i4 += 256) {
            int j  = i4 / 28;
            int ii = (i4 - j * 28) * 4;
            float4 w = Wsrc[i4];
            unsigned lo = bf16_rne(w.x) | (bf16_rne(w.y) << 16);
            unsigned hi = bf16_rne(w.z) | (bf16_rne(w.w) << 16);
            *(uint2*)&Wb[j * 136 + ii] = make_uint2(lo, hi);
        }
    }
    // stage x (transpose-gather) -> bf16 LDS
    for (int idx = tid; idx < 64 * 112; idx += 256) {
        int c  = idx / 448;
        int r  = idx - c * 448;
        int l  = r / 7;
        int dd = r - l * 7;
        xb[l * 136 + c * 7 + dd] =
            (unsigned short)bf16_rne(x[((n * CH + c) * LL + l0 + l) * DD + dd]);
    }
    // zero the K-pad region (cols 112..127 are read by the K=128 loop)
    for (int idx = tid; idx < 64 * 16; idx += 256)
        xb[(idx >> 4) * 136 + 112 + (idx & 15)] = 0;
    for (int idx = tid; idx < 112 * 16; idx += 256)
        Wb[(idx >> 4) * 136 + 112 + (idx & 15)] = 0;

    // zero pad slot 7 of this block's output rows (K/Q pads enter the attn dot)
    {
        size_t base = ((size_t)(mat * NB + n) * HH) * (LL * 8);
        for (int idx = tid; idx < 1024; idx += 256) {
            int hh = idx >> 6, l = idx & 63;
            qkvb[base + (size_t)(hh * LL + l0 + l) * 8 + 7] = 0;
        }
    }
    __syncthreads();

    int wv = tid >> 6, lane = tid & 63, l15 = lane & 15, l4 = lane >> 4;

    const unsigned short* Arow = xb + (wv * 16 + l15) * 136 + l4 * 8;
    v8s af[4];
    #pragma unroll
    for (int k4 = 0; k4 < 4; ++k4) af[k4] = *(const v8s*)(Arow + k4 * 32);

    v4f acc[7];
    #pragma unroll
    for (int jt = 0; jt < 7; ++jt) acc[jt] = (v4f){0.f, 0.f, 0.f, 0.f};

    #pragma unroll
    for (int jt = 0; jt < 7; ++jt) {
        const unsigned short* Brow = Wb + (jt * 16 + l15) * 136 + l4 * 8;
        #pragma unroll
        for (int k4 = 0; k4 < 4; ++k4) {
            v8s bf = *(const v8s*)(Brow + k4 * 32);
            acc[jt] = __builtin_amdgcn_mfma_f32_16x16x32_bf16(af[k4], bf, acc[jt], 0, 0, 0);
        }
    }

    const float scale = (mat == 0) ? 0.0450842200277801f /* log2(e)/32 */ : 1.0f;
    size_t mbase = ((size_t)(mat * NB + n) * HH) * (LL * 8);
    #pragma unroll
    for (int jt = 0; jt < 7; ++jt) {
        int j   = jt * 16 + l15;
        int hh  = j / 7;
        int dim = j - hh * 7;
        float bj = b[j];
        int lrow = l0 + wv * 16 + l4 * 4;
        size_t rb = mbase + (size_t)hh * (LL * 8) + (size_t)lrow * 8 + dim;
        #pragma unroll
        for (int r = 0; r < 4; ++r) {
            float val = (acc[jt][r] + bj) * scale;
            qkvb[rb + (size_t)r * 8] = (unsigned short)bf16_rne(val);
        }
    }
}

// ---------------------------------------------------------------------------
// Kernel 2: MFMA flash attention, FULLY REGISTER-RESIDENT P (no LDS round trip).
//  S^T = mfma_32x32x16(A=K, B=Q): lane(g5,l31) holds S^T[key][q=l31] for 16
//  keys, key = (reg&3)+8*(reg>>2)+4*g5. exp+pack in regs is ALREADY a valid
//  B-operand for the next 32x32x16: B k-index = 8*g5+j covers key set
//  K(k) = (k&3)+8*((k>>2)&1)+4*(k>>3) — that permutation is absorbed into
//  Vt's column order at staging (bits 2<->3 of the chunk-local key index).
//  PV: O^T = mfma(A=V^T rows 0..7 (+ones row 7), B=P^T). acc rows 0-3 (g5=0)
//  = dims 0-3, rows 4-7 (g5=1) = dims 4-6 + denominator (dim7 = ones).
// grid = NB*HH*8 = 1024 blocks (n,h,qtile 128), 256 thr; wave owns 32 q rows.
// LDS = 33 KB -> 4 blocks/CU (16 waves/CU).
// ---------------------------------------------------------------------------
__global__ __launch_bounds__(256, 4) void attn(
    const unsigned short* __restrict__ qkvb, float* __restrict__ out)
{
    __shared__ __align__(16) unsigned short Kl[LL * 8];     // 16 KB
    __shared__ __align__(16) unsigned short Vt[8 * 1048];   // 16.4 KB, slot-permuted

    int bx = blockIdx.x;
    int qt = bx & 7, h = (bx >> 3) & 15, n = bx >> 7;
    int tid  = threadIdx.x;
    int wave = tid >> 6, lane = tid & 63;
    int l31 = lane & 31, g5 = lane >> 5;

    const unsigned short* Qg = qkvb + (size_t)((0 * NB + n) * HH + h) * (LL * 8);
    const unsigned short* Kg = qkvb + (size_t)((1 * NB + n) * HH + h) * (LL * 8);
    const unsigned short* Vg = qkvb + (size_t)((2 * NB + n) * HH + h) * (LL * 8);

    {   // stage K -> Kl (coalesced 16B)
        const uint4* Ks = (const uint4*)Kg;
        uint4* Kd = (uint4*)Kl;
        #pragma unroll
        for (int it = 0; it < 4; ++it) Kd[tid + it * 256] = Ks[tid + it * 256];
    }
    {   // transpose + slot-permute V: global -> regs -> Vt[8][1048]
        // thread t owns keys 4t..4t+3; slot = key with chunk-local bits 2<->3 swapped
        const uint4* Vs = (const uint4*)Vg;
        uint4 r0 = Vs[4 * tid], r1 = Vs[4 * tid + 1];
        uint4 r2 = Vs[4 * tid + 2], r3 = Vs[4 * tid + 3];
        const unsigned* p0 = (const unsigned*)&r0;
        const unsigned* p1 = (const unsigned*)&r1;
        const unsigned* p2 = (const unsigned*)&r2;
        const unsigned* p3 = (const unsigned*)&r3;
        int col = ((tid >> 3) << 5) + ((tid & 1) << 3) + (((tid >> 1) & 1) << 2)
                + (((tid >> 2) & 1) << 4);
        #pragma unroll
        for (int d = 0; d < 7; ++d) {
            unsigned a0 = p0[d >> 1], a1 = p1[d >> 1], a2 = p2[d >> 1], a3 = p3[d >> 1];
            unsigned w0, w1;
            if (d & 1) { w0 = (a0 >> 16) | (a1 & 0xffff0000u); w1 = (a2 >> 16) | (a3 & 0xffff0000u); }
            else       { w0 = (a0 & 0xffffu) | (a1 << 16);     w1 = (a2 & 0xffffu) | (a3 << 16); }
            *(uint2*)&Vt[d * 1048 + col] = make_uint2(w0, w1);
        }
        *(uint2*)&Vt[7 * 1048 + col] = make_uint2(0x3f803f80u, 0x3f803f80u);  // ones row
    }
    __syncthreads();

    int q = qt * 128 + wave * 32 + l31;
    v8s zero8 = {0, 0, 0, 0, 0, 0, 0, 0};
    v8s qf = (lane < 32) ? *(const v8s*)(Qg + (size_t)q * 8) : zero8;

    const unsigned short* Vrow = Vt + (l31 & 7) * 1048 + g5 * 8;  // rows 8+ -> garbage, ignored
    v16f acc = {};

    v8s kf = (lane < 32) ? *(const v8s*)(Kl + l31 * 8) : zero8;   // chunk 0 prefetch

    #pragma unroll 4
    for (int c = 0; c < 32; ++c) {
        v16f s = __builtin_amdgcn_mfma_f32_32x32x16_bf16(kf, qf, (v16f){}, 0, 0, 0);
        if (c < 31)
            kf = (lane < 32) ? *(const v8s*)(Kl + ((c + 1) * 32 + l31) * 8) : zero8;
        v8s va1 = *(const v8s*)(Vrow + c * 32);        // k=0..15 (slots)
        v8s va2 = *(const v8s*)(Vrow + c * 32 + 16);   // k=16..31

        unsigned pk[8];
        #pragma unroll
        for (int p = 0; p < 8; ++p)
            pk[p] = pack_trunc(EXP2F(s[2 * p]), EXP2F(s[2 * p + 1]));
        v8s pA = __builtin_bit_cast(v8s, (v4u){pk[0], pk[1], pk[2], pk[3]});
        v8s pB = __builtin_bit_cast(v8s, (v4u){pk[4], pk[5], pk[6], pk[7]});

        acc = __builtin_amdgcn_mfma_f32_32x32x16_bf16(va1, pA, acc, 0, 0, 0);
        acc = __builtin_amdgcn_mfma_f32_32x32x16_bf16(va2, pB, acc, 0, 0, 0);
    }

    // epilogue: acc reg r = O^T[dim = 4*g5 + r][q] (pre-normalize);
    // denominator = O^T[7][q] = upper-half lanes' reg 3.
    float rs = __shfl(acc[3], 32 + l31, 64);
    float* base = out + (size_t)(n * HH + h) * LL * 7 + (size_t)q * 7;
    #pragma unroll
    for (int r = 0; r < 4; ++r) {
        int dim = 4 * g5 + r;
        if (dim < 7) base[dim] = acc[r] / rs;
    }
}

extern "C" void kernel_launch(void* const* d_in, const int* in_sizes, int n_in,
                              void* d_out, int out_size, void* d_ws, size_t ws_size,
                              hipStream_t stream) {
    const float* x  = (const float*)d_in[0];
    const float* Wq = (const float*)d_in[1];
    const float* bq = (const float*)d_in[2];
    const float* Wk = (const float*)d_in[3];
    const float* bk = (const float*)d_in[4];
    const float* Wv = (const float*)d_in[5];
    const float* bv = (const float*)d_in[6];
    unsigned short* qkvb = (unsigned short*)d_ws;  // [3][8][16][1024][8] bf16 = 6 MB
    float* o = (float*)d_out;

    qkv_proj<<<dim3(3 * NB * 16), dim3(256), 0, stream>>>(x, Wq, bq, Wk, bk, Wv, bv, qkvb);
    attn<<<dim3(NB * HH * 8), dim3(256), 0, stream>>>(qkvb, o);
}

// Round 7
// 100.615 us; speedup vs baseline: 1.4783x; 1.0094x over previous
//
#include <hip/hip_runtime.h>
#include <math.h>

#define NB 8
#define CH 16
#define LL 1024
#define DD 7
#define HH 16

typedef float    v2f  __attribute__((ext_vector_type(2)));
typedef float    v4f  __attribute__((ext_vector_type(4)));
typedef float    v16f __attribute__((ext_vector_type(16)));
typedef short    v8s  __attribute__((ext_vector_type(8)));
typedef unsigned v4u  __attribute__((ext_vector_type(4)));

#if __has_builtin(__builtin_amdgcn_exp2f)
#define EXP2F(x) __builtin_amdgcn_exp2f(x)
#else
#define EXP2F(x) exp2f(x)
#endif

__device__ inline unsigned bf16_rne(float f) {
    unsigned u = __builtin_bit_cast(unsigned, f);
    return (u + 0x7fffu + ((u >> 16) & 1u)) >> 16;
}
__device__ inline unsigned pack_trunc(float a, float b) {
    unsigned ua = __builtin_bit_cast(unsigned, a);
    unsigned ub = __builtin_bit_cast(unsigned, b);
    return (ua >> 16) | (ub & 0xffff0000u);
}

// ---------------------------------------------------------------------------
// Kernel 1: QKV projection via MFMA (bf16 inputs, fp32 accumulate).
//  C[l][j] = sum_i xf[l][i] * W[j][i]; A = x (m=l), B = W (n=j), K padded to
//  128 with zeros. LDS: xb[64][136] bf16, Wb[112][136] bf16. Wave owns 16
//  l-rows: A-frags loaded once, reused over 7 j-tiles x 4 K-slices = 28 MFMA.
//  Epilogue: +bias, Q scaled by log2(e)/32, bf16 store; pad slot 7 zeroed.
// grid = 3*NB*16 = 384 blocks, 256 threads.
// ---------------------------------------------------------------------------
__global__ __launch_bounds__(256, 2) void qkv_proj(
    const float* __restrict__ x,
    const float* __restrict__ Wq, const float* __restrict__ bq,
    const float* __restrict__ Wk, const float* __restrict__ bk,
    const float* __restrict__ Wv, const float* __restrict__ bv,
    unsigned short* __restrict__ qkvb)
{
    __shared__ __align__(16) unsigned short Wb[112 * 136];  // 29.8 KB
    __shared__ __align__(16) unsigned short xb[64 * 136];   // 17.0 KB

    int bx  = blockIdx.x;
    int mat = bx / (NB * 16);
    int rem = bx % (NB * 16);
    int n   = rem / 16;
    int l0  = (rem % 16) * 64;

    const float* W = (mat == 0) ? Wq : (mat == 1) ? Wk : Wv;
    const float* b = (mat == 0) ? bq : (mat == 1) ? bk : bv;

    int tid = threadIdx.x;

    // stage W -> bf16 LDS (float4 reads, uint2 writes)
    {
        const float4* Wsrc = (const float4*)W;
        for (int i4 = tid; i4 < 3136; i4 += 256) {
            int j  = i4 / 28;
            int ii = (i4 - j * 28) * 4;
            float4 w = Wsrc[i4];
            unsigned lo = bf16_rne(w.x) | (bf16_rne(w.y) << 16);
            unsigned hi = bf16_rne(w.z) | (bf16_rne(w.w) << 16);
            *(uint2*)&Wb[j * 136 + ii] = make_uint2(lo, hi);
        }
    }
    // stage x (transpose-gather) -> bf16 LDS
    for (int idx = tid; idx < 64 * 112; idx += 256) {
        int c  = idx / 448;
        int r  = idx - c * 448;
        int l  = r / 7;
        int dd = r - l * 7;
        xb[l * 136 + c * 7 + dd] =
            (unsigned short)bf16_rne(x[((n * CH + c) * LL + l0 + l) * DD + dd]);
    }
    // zero the K-pad region (cols 112..127 are read by the K=128 loop)
    for (int idx = tid; idx < 64 * 16; idx += 256)
        xb[(idx >> 4) * 136 + 112 + (idx & 15)] = 0;
    for (int idx = tid; idx < 112 * 16; idx += 256)
        Wb[(idx >> 4) * 136 + 112 + (idx & 15)] = 0;

    // zero pad slot 7 of this block's output rows (K/Q pads enter the attn dot)
    {
        size_t base = ((size_t)(mat * NB + n) * HH) * (LL * 8);
        for (int idx = tid; idx < 1024; idx += 256) {
            int hh = idx >> 6, l = idx & 63;
            qkvb[base + (size_t)(hh * LL + l0 + l) * 8 + 7] = 0;
        }
    }
    __syncthreads();

    int wv = tid >> 6, lane = tid & 63, l15 = lane & 15, l4 = lane >> 4;

    const unsigned short* Arow = xb + (wv * 16 + l15) * 136 + l4 * 8;
    v8s af[4];
    #pragma unroll
    for (int k4 = 0; k4 < 4; ++k4) af[k4] = *(const v8s*)(Arow + k4 * 32);

    v4f acc[7];
    #pragma unroll
    for (int jt = 0; jt < 7; ++jt) acc[jt] = (v4f){0.f, 0.f, 0.f, 0.f};

    #pragma unroll
    for (int jt = 0; jt < 7; ++jt) {
        const unsigned short* Brow = Wb + (jt * 16 + l15) * 136 + l4 * 8;
        #pragma unroll
        for (int k4 = 0; k4 < 4; ++k4) {
            v8s bf = *(const v8s*)(Brow + k4 * 32);
            acc[jt] = __builtin_amdgcn_mfma_f32_16x16x32_bf16(af[k4], bf, acc[jt], 0, 0, 0);
        }
    }

    const float scale = (mat == 0) ? 0.0450842200277801f /* log2(e)/32 */ : 1.0f;
    size_t mbase = ((size_t)(mat * NB + n) * HH) * (LL * 8);
    #pragma unroll
    for (int jt = 0; jt < 7; ++jt) {
        int j   = jt * 16 + l15;
        int hh  = j / 7;
        int dim = j - hh * 7;
        float bj = b[j];
        int lrow = l0 + wv * 16 + l4 * 4;
        size_t rb = mbase + (size_t)hh * (LL * 8) + (size_t)lrow * 8 + dim;
        #pragma unroll
        for (int r = 0; r < 4; ++r) {
            float val = (acc[jt][r] + bj) * scale;
            qkvb[rb + (size_t)r * 8] = (unsigned short)bf16_rne(val);
        }
    }
}

// ---------------------------------------------------------------------------
// Kernel 2: MFMA flash attention, register-resident P; each wave owns 64 q
// rows (two 32-q groups share every kf/va LDS load -> half the LDS traffic
// per score, 32-long exp runs keep the trans pipe dense).
//  S^T = mfma_32x32x16(A=K, B=Q); exp+pack in regs is directly the B-operand
//  of the PV mfma; the required key permutation (chunk-local bits 2<->3) is
//  absorbed into Vt's column order at staging. V row 7 == 1.0 gives the
//  softmax denominator in the upper lanes' reg 3.
// grid = NB*HH*4 = 512 blocks (n,h,qtile 256), 256 thr (4 waves) -> 2 blk/CU.
// LDS = 33 KB.
// ---------------------------------------------------------------------------
__global__ __launch_bounds__(256, 2) void attn(
    const unsigned short* __restrict__ qkvb, float* __restrict__ out)
{
    __shared__ __align__(16) unsigned short Kl[LL * 8];     // 16 KB
    __shared__ __align__(16) unsigned short Vt[8 * 1048];   // 16.4 KB, slot-permuted

    int bx = blockIdx.x;
    int qt = bx & 3, h = (bx >> 2) & 15, n = bx >> 6;
    int tid  = threadIdx.x;
    int wave = tid >> 6, lane = tid & 63;
    int l31 = lane & 31, g5 = lane >> 5;

    const unsigned short* Qg = qkvb + (size_t)((0 * NB + n) * HH + h) * (LL * 8);
    const unsigned short* Kg = qkvb + (size_t)((1 * NB + n) * HH + h) * (LL * 8);
    const unsigned short* Vg = qkvb + (size_t)((2 * NB + n) * HH + h) * (LL * 8);

    {   // stage K -> Kl (coalesced 16B)
        const uint4* Ks = (const uint4*)Kg;
        uint4* Kd = (uint4*)Kl;
        #pragma unroll
        for (int it = 0; it < 4; ++it) Kd[tid + it * 256] = Ks[tid + it * 256];
    }
    {   // transpose + slot-permute V: global -> regs -> Vt[8][1048]
        const uint4* Vs = (const uint4*)Vg;
        uint4 r0 = Vs[4 * tid], r1 = Vs[4 * tid + 1];
        uint4 r2 = Vs[4 * tid + 2], r3 = Vs[4 * tid + 3];
        const unsigned* p0 = (const unsigned*)&r0;
        const unsigned* p1 = (const unsigned*)&r1;
        const unsigned* p2 = (const unsigned*)&r2;
        const unsigned* p3 = (const unsigned*)&r3;
        int col = ((tid >> 3) << 5) + ((tid & 1) << 3) + (((tid >> 1) & 1) << 2)
                + (((tid >> 2) & 1) << 4);
        #pragma unroll
        for (int d = 0; d < 7; ++d) {
            unsigned a0 = p0[d >> 1], a1 = p1[d >> 1], a2 = p2[d >> 1], a3 = p3[d >> 1];
            unsigned w0, w1;
            if (d & 1) { w0 = (a0 >> 16) | (a1 & 0xffff0000u); w1 = (a2 >> 16) | (a3 & 0xffff0000u); }
            else       { w0 = (a0 & 0xffffu) | (a1 << 16);     w1 = (a2 & 0xffffu) | (a3 << 16); }
            *(uint2*)&Vt[d * 1048 + col] = make_uint2(w0, w1);
        }
        *(uint2*)&Vt[7 * 1048 + col] = make_uint2(0x3f803f80u, 0x3f803f80u);  // ones row
    }
    __syncthreads();

    int q0 = qt * 256 + wave * 64 + l31;      // q group A
    v8s zero8 = {0, 0, 0, 0, 0, 0, 0, 0};
    v8s qfA = (lane < 32) ? *(const v8s*)(Qg + (size_t)q0 * 8)        : zero8;
    v8s qfB = (lane < 32) ? *(const v8s*)(Qg + (size_t)(q0 + 32) * 8) : zero8;

    const unsigned short* Vrow = Vt + (l31 & 7) * 1048 + g5 * 8;
    v16f accA = {}, accB = {};

    v8s kf = (lane < 32) ? *(const v8s*)(Kl + l31 * 8) : zero8;   // chunk 0 prefetch

    #pragma unroll 2
    for (int c = 0; c < 32; ++c) {
        v16f sA = __builtin_amdgcn_mfma_f32_32x32x16_bf16(kf, qfA, (v16f){}, 0, 0, 0);
        v16f sB = __builtin_amdgcn_mfma_f32_32x32x16_bf16(kf, qfB, (v16f){}, 0, 0, 0);
        if (c < 31)
            kf = (lane < 32) ? *(const v8s*)(Kl + ((c + 1) * 32 + l31) * 8) : zero8;
        v8s va1 = *(const v8s*)(Vrow + c * 32);        // slots 0..15
        v8s va2 = *(const v8s*)(Vrow + c * 32 + 16);   // slots 16..31

        unsigned pkA[8], pkB[8];
        #pragma unroll
        for (int p = 0; p < 8; ++p)
            pkA[p] = pack_trunc(EXP2F(sA[2 * p]), EXP2F(sA[2 * p + 1]));
        #pragma unroll
        for (int p = 0; p < 8; ++p)
            pkB[p] = pack_trunc(EXP2F(sB[2 * p]), EXP2F(sB[2 * p + 1]));

        v8s pA1 = __builtin_bit_cast(v8s, (v4u){pkA[0], pkA[1], pkA[2], pkA[3]});
        v8s pA2 = __builtin_bit_cast(v8s, (v4u){pkA[4], pkA[5], pkA[6], pkA[7]});
        v8s pB1 = __builtin_bit_cast(v8s, (v4u){pkB[0], pkB[1], pkB[2], pkB[3]});
        v8s pB2 = __builtin_bit_cast(v8s, (v4u){pkB[4], pkB[5], pkB[6], pkB[7]});

        accA = __builtin_amdgcn_mfma_f32_32x32x16_bf16(va1, pA1, accA, 0, 0, 0);
        accA = __builtin_amdgcn_mfma_f32_32x32x16_bf16(va2, pA2, accA, 0, 0, 0);
        accB = __builtin_amdgcn_mfma_f32_32x32x16_bf16(va1, pB1, accB, 0, 0, 0);
        accB = __builtin_amdgcn_mfma_f32_32x32x16_bf16(va2, pB2, accB, 0, 0, 0);
    }

    // epilogue: acc reg r = O^T[dim = 4*g5 + r][q] (pre-normalize);
    // denominator = O^T[7][q] = upper-half lanes' reg 3.
    size_t hb = (size_t)(n * HH + h) * LL * 7;
    {
        float rs = __shfl(accA[3], 32 + l31, 64);
        float* base = out + hb + (size_t)q0 * 7;
        #pragma unroll
        for (int r = 0; r < 4; ++r) {
            int dim = 4 * g5 + r;
            if (dim < 7) base[dim] = accA[r] / rs;
        }
    }
    {
        float rs = __shfl(accB[3], 32 + l31, 64);
        float* base = out + hb + (size_t)(q0 + 32) * 7;
        #pragma unroll
        for (int r = 0; r < 4; ++r) {
            int dim = 4 * g5 + r;
            if (dim < 7) base[dim] = accB[r] / rs;
        }
    }
}

extern "C" void kernel_launch(void* const* d_in, const int* in_sizes, int n_in,
                              void* d_out, int out_size, void* d_ws, size_t ws_size,
                              hipStream_t stream) {
    const float* x  = (const float*)d_in[0];
    const float* Wq = (const float*)d_in[1];
    const float* bq = (const float*)d_in[2];
    const float* Wk = (const float*)d_in[3];
    const float* bk = (const float*)d_in[4];
    const float* Wv = (const float*)d_in[5];
    const float* bv = (const float*)d_in[6];
    unsigned short* qkvb = (unsigned short*)d_ws;  // [3][8][16][1024][8] bf16 = 6 MB
    float* o = (float*)d_out;

    qkv_proj<<<dim3(3 * NB * 16), dim3(256), 0, stream>>>(x, Wq, bq, Wk, bk, Wv, bv, qkvb);
    attn<<<dim3(NB * HH * 4), dim3(256), 0, stream>>>(qkvb, o);
}

// Round 8
// 99.470 us; speedup vs baseline: 1.4953x; 1.0115x over previous
//
#include <hip/hip_runtime.h>
#include <math.h>

#define NB 8
#define CH 16
#define LL 1024
#define DD 7
#define HH 16

typedef float    v2f  __attribute__((ext_vector_type(2)));
typedef float    v4f  __attribute__((ext_vector_type(4)));
typedef float    v16f __attribute__((ext_vector_type(16)));
typedef short    v8s  __attribute__((ext_vector_type(8)));
typedef unsigned v4u  __attribute__((ext_vector_type(4)));

#if __has_builtin(__builtin_amdgcn_exp2f)
#define EXP2F(x) __builtin_amdgcn_exp2f(x)
#else
#define EXP2F(x) exp2f(x)
#endif

__device__ inline unsigned bf16_rne(float f) {
    unsigned u = __builtin_bit_cast(unsigned, f);
    return (u + 0x7fffu + ((u >> 16) & 1u)) >> 16;
}
__device__ inline unsigned pack_trunc(float a, float b) {
    unsigned ua = __builtin_bit_cast(unsigned, a);
    unsigned ub = __builtin_bit_cast(unsigned, b);
    return (ua >> 16) | (ub & 0xffff0000u);
}

// ---------------------------------------------------------------------------
// Kernel 1: QKV projection via MFMA (bf16 inputs, fp32 accumulate). Unchanged
// from r6 (measured ~3 us). Output padded bf16 [mat][n][h][1024][8], Q
// pre-scaled by log2(e)/32, pad slot 7 zeroed.
// grid = 3*NB*16 = 384 blocks, 256 threads.
// ---------------------------------------------------------------------------
__global__ __launch_bounds__(256, 2) void qkv_proj(
    const float* __restrict__ x,
    const float* __restrict__ Wq, const float* __restrict__ bq,
    const float* __restrict__ Wk, const float* __restrict__ bk,
    const float* __restrict__ Wv, const float* __restrict__ bv,
    unsigned short* __restrict__ qkvb)
{
    __shared__ __align__(16) unsigned short Wb[112 * 136];  // 29.8 KB
    __shared__ __align__(16) unsigned short xb[64 * 136];   // 17.0 KB

    int bx  = blockIdx.x;
    int mat = bx / (NB * 16);
    int rem = bx % (NB * 16);
    int n   = rem / 16;
    int l0  = (rem % 16) * 64;

    const float* W = (mat == 0) ? Wq : (mat == 1) ? Wk : Wv;
    const float* b = (mat == 0) ? bq : (mat == 1) ? bk : bv;

    int tid = threadIdx.x;

    {
        const float4* Wsrc = (const float4*)W;
        for (int i4 = tid; i4 < 3136; i4 += 256) {
            int j  = i4 / 28;
            int ii = (i4 - j * 28) * 4;
            float4 w = Wsrc[i4];
            unsigned lo = bf16_rne(w.x) | (bf16_rne(w.y) << 16);
            unsigned hi = bf16_rne(w.z) | (bf16_rne(w.w) << 16);
            *(uint2*)&Wb[j * 136 + ii] = make_uint2(lo, hi);
        }
    }
    for (int idx = tid; idx < 64 * 112; idx += 256) {
        int c  = idx / 448;
        int r  = idx - c * 448;
        int l  = r / 7;
        int dd = r - l * 7;
        xb[l * 136 + c * 7 + dd] =
            (unsigned short)bf16_rne(x[((n * CH + c) * LL + l0 + l) * DD + dd]);
    }
    for (int idx = tid; idx < 64 * 16; idx += 256)
        xb[(idx >> 4) * 136 + 112 + (idx & 15)] = 0;
    for (int idx = tid; idx < 112 * 16; idx += 256)
        Wb[(idx >> 4) * 136 + 112 + (idx & 15)] = 0;

    {
        size_t base = ((size_t)(mat * NB + n) * HH) * (LL * 8);
        for (int idx = tid; idx < 1024; idx += 256) {
            int hh = idx >> 6, l = idx & 63;
            qkvb[base + (size_t)(hh * LL + l0 + l) * 8 + 7] = 0;
        }
    }
    __syncthreads();

    int wv = tid >> 6, lane = tid & 63, l15 = lane & 15, l4 = lane >> 4;

    const unsigned short* Arow = xb + (wv * 16 + l15) * 136 + l4 * 8;
    v8s af[4];
    #pragma unroll
    for (int k4 = 0; k4 < 4; ++k4) af[k4] = *(const v8s*)(Arow + k4 * 32);

    v4f acc[7];
    #pragma unroll
    for (int jt = 0; jt < 7; ++jt) acc[jt] = (v4f){0.f, 0.f, 0.f, 0.f};

    #pragma unroll
    for (int jt = 0; jt < 7; ++jt) {
        const unsigned short* Brow = Wb + (jt * 16 + l15) * 136 + l4 * 8;
        #pragma unroll
        for (int k4 = 0; k4 < 4; ++k4) {
            v8s bf = *(const v8s*)(Brow + k4 * 32);
            acc[jt] = __builtin_amdgcn_mfma_f32_16x16x32_bf16(af[k4], bf, acc[jt], 0, 0, 0);
        }
    }

    const float scale = (mat == 0) ? 0.0450842200277801f /* log2(e)/32 */ : 1.0f;
    size_t mbase = ((size_t)(mat * NB + n) * HH) * (LL * 8);
    #pragma unroll
    for (int jt = 0; jt < 7; ++jt) {
        int j   = jt * 16 + l15;
        int hh  = j / 7;
        int dim = j - hh * 7;
        float bj = b[j];
        int lrow = l0 + wv * 16 + l4 * 4;
        size_t rb = mbase + (size_t)hh * (LL * 8) + (size_t)lrow * 8 + dim;
        #pragma unroll
        for (int r = 0; r < 4; ++r) {
            float val = (acc[jt][r] + bj) * scale;
            qkvb[rb + (size_t)r * 8] = (unsigned short)bf16_rne(val);
        }
    }
}

// ---------------------------------------------------------------------------
// Kernel 2: MFMA flash attention, register-resident P, SPLIT-K across waves.
//  512-thread blocks = 4 q-groups x 2 key-halves. Each wave: 64 q rows x 512
//  keys (r7's per-wave efficiency) but 16 waves/CU = 4 waves/SIMD (r6's
//  occupancy) to hide the S->exp->pack->PV dependency chain.
//  Key-half partials combine via LDS with plain fp32 adds (no max-rescale
//  softmax), kh=0 waves divide by the ones-row denominator and store.
// grid = NB*HH*4 = 512 blocks (n,h,qtile 256), 512 thr. LDS 41.3 KB -> 2/CU.
// ---------------------------------------------------------------------------
__global__ __launch_bounds__(512, 4) void attn(
    const unsigned short* __restrict__ qkvb, float* __restrict__ out)
{
    __shared__ __align__(16) unsigned short Kl[LL * 8];     // 16 KB
    __shared__ __align__(16) unsigned short Vt[8 * 1048];   // 16.4 KB, slot-permuted
    __shared__ __align__(16) float red[256 * 8];            // 8 KB partial exchange

    int bx = blockIdx.x;
    int qt = bx & 3, h = (bx >> 2) & 15, n = bx >> 6;
    int tid  = threadIdx.x;
    int wave = tid >> 6, lane = tid & 63;
    int l31 = lane & 31, g5 = lane >> 5;
    int g  = wave & 3;      // q-group
    int kh = wave >> 2;     // key half

    const unsigned short* Qg = qkvb + (size_t)((0 * NB + n) * HH + h) * (LL * 8);
    const unsigned short* Kg = qkvb + (size_t)((1 * NB + n) * HH + h) * (LL * 8);
    const unsigned short* Vg = qkvb + (size_t)((2 * NB + n) * HH + h) * (LL * 8);

    {   // stage K -> Kl (coalesced 16B, 1024 uint4 by 512 threads)
        const uint4* Ks = (const uint4*)Kg;
        uint4* Kd = (uint4*)Kl;
        Kd[tid]       = Ks[tid];
        Kd[tid + 512] = Ks[tid + 512];
    }
    if (tid < 256) {   // transpose + slot-permute V: global -> regs -> Vt[8][1048]
        const uint4* Vs = (const uint4*)Vg;
        uint4 r0 = Vs[4 * tid], r1 = Vs[4 * tid + 1];
        uint4 r2 = Vs[4 * tid + 2], r3 = Vs[4 * tid + 3];
        const unsigned* p0 = (const unsigned*)&r0;
        const unsigned* p1 = (const unsigned*)&r1;
        const unsigned* p2 = (const unsigned*)&r2;
        const unsigned* p3 = (const unsigned*)&r3;
        int col = ((tid >> 3) << 5) + ((tid & 1) << 3) + (((tid >> 1) & 1) << 2)
                + (((tid >> 2) & 1) << 4);
        #pragma unroll
        for (int d = 0; d < 7; ++d) {
            unsigned a0 = p0[d >> 1], a1 = p1[d >> 1], a2 = p2[d >> 1], a3 = p3[d >> 1];
            unsigned w0, w1;
            if (d & 1) { w0 = (a0 >> 16) | (a1 & 0xffff0000u); w1 = (a2 >> 16) | (a3 & 0xffff0000u); }
            else       { w0 = (a0 & 0xffffu) | (a1 << 16);     w1 = (a2 & 0xffffu) | (a3 << 16); }
            *(uint2*)&Vt[d * 1048 + col] = make_uint2(w0, w1);
        }
        *(uint2*)&Vt[7 * 1048 + col] = make_uint2(0x3f803f80u, 0x3f803f80u);  // ones row
    }
    __syncthreads();

    int q0 = qt * 256 + g * 64 + l31;
    v8s zero8 = {0, 0, 0, 0, 0, 0, 0, 0};
    v8s qfA = (lane < 32) ? *(const v8s*)(Qg + (size_t)q0 * 8)        : zero8;
    v8s qfB = (lane < 32) ? *(const v8s*)(Qg + (size_t)(q0 + 32) * 8) : zero8;

    const unsigned short* Vrow = Vt + (l31 & 7) * 1048 + g5 * 8;
    v16f accA = {}, accB = {};

    int kbase = kh * 512;   // this wave's 512 keys
    v8s kf = (lane < 32) ? *(const v8s*)(Kl + (kbase + l31) * 8) : zero8;

    #pragma unroll 2
    for (int c = 0; c < 16; ++c) {
        v16f sA = __builtin_amdgcn_mfma_f32_32x32x16_bf16(kf, qfA, (v16f){}, 0, 0, 0);
        v16f sB = __builtin_amdgcn_mfma_f32_32x32x16_bf16(kf, qfB, (v16f){}, 0, 0, 0);
        if (c < 15)
            kf = (lane < 32) ? *(const v8s*)(Kl + (kbase + (c + 1) * 32 + l31) * 8) : zero8;
        v8s va1 = *(const v8s*)(Vrow + (kbase + c * 32));        // slots 0..15
        v8s va2 = *(const v8s*)(Vrow + (kbase + c * 32) + 16);   // slots 16..31

        unsigned pkA[8], pkB[8];
        #pragma unroll
        for (int p = 0; p < 8; ++p)
            pkA[p] = pack_trunc(EXP2F(sA[2 * p]), EXP2F(sA[2 * p + 1]));
        #pragma unroll
        for (int p = 0; p < 8; ++p)
            pkB[p] = pack_trunc(EXP2F(sB[2 * p]), EXP2F(sB[2 * p + 1]));

        v8s pA1 = __builtin_bit_cast(v8s, (v4u){pkA[0], pkA[1], pkA[2], pkA[3]});
        v8s pA2 = __builtin_bit_cast(v8s, (v4u){pkA[4], pkA[5], pkA[6], pkA[7]});
        v8s pB1 = __builtin_bit_cast(v8s, (v4u){pkB[0], pkB[1], pkB[2], pkB[3]});
        v8s pB2 = __builtin_bit_cast(v8s, (v4u){pkB[4], pkB[5], pkB[6], pkB[7]});

        accA = __builtin_amdgcn_mfma_f32_32x32x16_bf16(va1, pA1, accA, 0, 0, 0);
        accA = __builtin_amdgcn_mfma_f32_32x32x16_bf16(va2, pA2, accA, 0, 0, 0);
        accB = __builtin_amdgcn_mfma_f32_32x32x16_bf16(va1, pB1, accB, 0, 0, 0);
        accB = __builtin_amdgcn_mfma_f32_32x32x16_bf16(va2, pB2, accB, 0, 0, 0);
    }

    // combine key halves: kh=1 writes regs 0..3 (dims 4*g5..4*g5+3), kh=0 adds
    if (kh == 1) {
        *(float4*)&red[(size_t)(g * 64 + l31) * 8 + 4 * g5] =
            make_float4(accA[0], accA[1], accA[2], accA[3]);
        *(float4*)&red[(size_t)(g * 64 + 32 + l31) * 8 + 4 * g5] =
            make_float4(accB[0], accB[1], accB[2], accB[3]);
    }
    __syncthreads();
    if (kh == 0) {
        float4 pa = *(const float4*)&red[(size_t)(g * 64 + l31) * 8 + 4 * g5];
        float4 pb = *(const float4*)&red[(size_t)(g * 64 + 32 + l31) * 8 + 4 * g5];
        accA[0] += pa.x; accA[1] += pa.y; accA[2] += pa.z; accA[3] += pa.w;
        accB[0] += pb.x; accB[1] += pb.y; accB[2] += pb.z; accB[3] += pb.w;

        size_t hb = (size_t)(n * HH + h) * LL * 7;
        {
            float rs = __shfl(accA[3], 32 + l31, 64);   // combined denominator
            float* base = out + hb + (size_t)q0 * 7;
            #pragma unroll
            for (int r = 0; r < 4; ++r) {
                int dim = 4 * g5 + r;
                if (dim < 7) base[dim] = accA[r] / rs;
            }
        }
        {
            float rs = __shfl(accB[3], 32 + l31, 64);
            float* base = out + hb + (size_t)(q0 + 32) * 7;
            #pragma unroll
            for (int r = 0; r < 4; ++r) {
                int dim = 4 * g5 + r;
                if (dim < 7) base[dim] = accB[r] / rs;
            }
        }
    }
}

extern "C" void kernel_launch(void* const* d_in, const int* in_sizes, int n_in,
                              void* d_out, int out_size, void* d_ws, size_t ws_size,
                              hipStream_t stream) {
    const float* x  = (const float*)d_in[0];
    const float* Wq = (const float*)d_in[1];
    const float* bq = (const float*)d_in[2];
    const float* Wk = (const float*)d_in[3];
    const float* bk = (const float*)d_in[4];
    const float* Wv = (const float*)d_in[5];
    const float* bv = (const float*)d_in[6];
    unsigned short* qkvb = (unsigned short*)d_ws;  // [3][8][16][1024][8] bf16 = 6 MB
    float* o = (float*)d_out;

    qkv_proj<<<dim3(3 * NB * 16), dim3(256), 0, stream>>>(x, Wq, bq, Wk, bk, Wv, bv, qkvb);
    attn<<<dim3(NB * HH * 4), dim3(512), 0, stream>>>(qkvb, o);
}